// Round 1
// baseline (1287.364 us; speedup 1.0000x reference)
//
#include <hip/hip_runtime.h>

#define DIN 128      // D_IN == N_HEADS*D_HEAD == 128
#define NHEADS 8
#define DHEAD 16
#define NPB 32       // nodes per block
#define EPB 32       // edges per block

__device__ __forceinline__ float clip5(float x) {
    return fminf(fmaxf(x, -5.0f), 5.0f);
}

// acc[i] (i=0..3, rows r0..r0+3) += xs[r0+i][:] @ W[:, cg*4 .. cg*4+3]
// xs reads are wave-broadcast (address independent of lane); W reads are
// coalesced float4 across the 32 cg lanes and L1/L2-resident (64 KB).
__device__ __forceinline__ void tile_gemm(const float xs[][DIN], int r0, int cg,
                                          const float* __restrict__ W,
                                          float4 acc[4]) {
#pragma unroll 4
    for (int kk = 0; kk < DIN; kk += 4) {
        float4 a[4];
#pragma unroll
        for (int i = 0; i < 4; ++i)
            a[i] = *(const float4*)&xs[r0 + i][kk];
#pragma unroll
        for (int t = 0; t < 4; ++t) {
            float4 w = *(const float4*)&W[(kk + t) * DIN + (cg << 2)];
#pragma unroll
            for (int i = 0; i < 4; ++i) {
                float av = ((const float*)&a[i])[t];
                acc[i].x = fmaf(av, w.x, acc[i].x);
                acc[i].y = fmaf(av, w.y, acc[i].y);
                acc[i].z = fmaf(av, w.z, acc[i].z);
                acc[i].w = fmaf(av, w.w, acc[i].w);
            }
        }
    }
}

__global__ __launch_bounds__(256) void node_proj_kernel(
    const float* __restrict__ x, const float* __restrict__ WQ,
    const float* __restrict__ WK, const float* __restrict__ WV,
    float* __restrict__ q, float* __restrict__ k, float* __restrict__ v,
    int N) {
    __shared__ float xs[NPB][DIN];
    const int tid = threadIdx.x;
    const int n0 = blockIdx.x * NPB;

#pragma unroll
    for (int i = 0; i < NPB * DIN / (256 * 4); ++i) {   // 4 iters, float4 each
        int idx = (tid + i * 256) * 4;
        int r = idx / DIN, c = idx % DIN;
        float4 val = make_float4(0.f, 0.f, 0.f, 0.f);
        if (n0 + r < N) val = *(const float4*)&x[(long)(n0 + r) * DIN + c];
        *(float4*)&xs[r][c] = val;
    }
    __syncthreads();

    const int cg = tid & 31;        // output column group: cols cg*4..cg*4+3
    const int ng = tid >> 5;        // row group: rows ng*4..ng*4+3
    const int r0 = ng * 4;

    const float* Ws[3] = {WQ, WK, WV};
    float* outs[3] = {q, k, v};
#pragma unroll
    for (int m = 0; m < 3; ++m) {
        float4 acc[4] = {make_float4(0,0,0,0), make_float4(0,0,0,0),
                         make_float4(0,0,0,0), make_float4(0,0,0,0)};
        tile_gemm(xs, r0, cg, Ws[m], acc);
#pragma unroll
        for (int i = 0; i < 4; ++i) {
            int n = n0 + r0 + i;
            if (n < N)
                *(float4*)&outs[m][(long)n * DIN + (cg << 2)] = acc[i];
        }
    }
}

__global__ __launch_bounds__(256) void edge_kernel(
    const float* __restrict__ edge_attr, const int* __restrict__ edge_index,
    const float* __restrict__ WE, const float* __restrict__ q,
    const float* __restrict__ k, const float* __restrict__ v,
    float* __restrict__ e_out, float* __restrict__ wV, float* __restrict__ z,
    int E) {
    __shared__ float eas[EPB][DIN];
    __shared__ int rows[EPB], cols[EPB];
    const int tid = threadIdx.x;
    const int e0 = blockIdx.x * EPB;

    if (tid < EPB) {
        int e = e0 + tid;
        rows[tid] = (e < E) ? edge_index[e] : 0;
        cols[tid] = (e < E) ? edge_index[E + e] : 0;
    }
#pragma unroll
    for (int i = 0; i < EPB * DIN / (256 * 4); ++i) {
        int idx = (tid + i * 256) * 4;
        int r = idx / DIN, c = idx % DIN;
        float4 val = make_float4(0.f, 0.f, 0.f, 0.f);
        if (e0 + r < E) val = *(const float4*)&edge_attr[(long)(e0 + r) * DIN + c];
        *(float4*)&eas[r][c] = val;
    }
    __syncthreads();

    const int cg = tid & 31;
    const int ng = tid >> 5;
    const int r0 = ng * 4;

    float4 acc[4] = {make_float4(0,0,0,0), make_float4(0,0,0,0),
                     make_float4(0,0,0,0), make_float4(0,0,0,0)};
    tile_gemm(eas, r0, cg, WE, acc);   // acc[i] = e_proj for edge r0+i, cols cg*4..+3

    const int h = cg >> 2;             // cols cg*4..cg*4+3 all lie in head cg>>2
#pragma unroll
    for (int i = 0; i < 4; ++i) {
        int el = r0 + i;
        if (e0 + el >= E) continue;    // whole 4-lane shuffle group exits together
        int er = rows[el], ec = cols[el];
        float4 kv = *(const float4*)&k[(long)er * DIN + (cg << 2)];
        float4 qv = *(const float4*)&q[(long)ec * DIN + (cg << 2)];
        float4 t;
        t.x = clip5(kv.x * qv.x * 0.25f) * acc[i].x;
        t.y = clip5(kv.y * qv.y * 0.25f) * acc[i].y;
        t.z = clip5(kv.z * qv.z * 0.25f) * acc[i].z;
        t.w = clip5(kv.w * qv.w * 0.25f) * acc[i].w;
        *(float4*)&e_out[(long)(e0 + el) * DIN + (cg << 2)] = t;

        float s = t.x + t.y + t.z + t.w;          // partial head-sum (4 of 16 dims)
        s += __shfl_xor(s, 1);                    // reduce across the 4 lanes
        s += __shfl_xor(s, 2);                    // covering this head's 16 dims
        float ax = expf(clip5(s));

        float4 vv = *(const float4*)&v[(long)er * DIN + (cg << 2)];
        float* wp = &wV[(long)ec * DIN + (cg << 2)];
        atomicAdd(wp + 0, vv.x * ax);
        atomicAdd(wp + 1, vv.y * ax);
        atomicAdd(wp + 2, vv.z * ax);
        atomicAdd(wp + 3, vv.w * ax);
        if ((cg & 3) == 0) atomicAdd(&z[(long)ec * NHEADS + h], ax);
    }
}

__global__ __launch_bounds__(256) void normalize_kernel(
    float* __restrict__ hbuf, const float* __restrict__ z, int N) {
    long idx = (long)blockIdx.x * blockDim.x + threadIdx.x;
    long base = idx * 4;
    if (base >= (long)N * DIN) return;
    int n = (int)(base / DIN);
    int c = (int)(base % DIN);                 // 4-aligned, head = c>>4 for all 4
    float zz = z[n * NHEADS + (c >> 4)] + 1e-6f;
    float inv = 1.0f / zz;
    float4 val = *(float4*)&hbuf[base];
    val.x *= inv; val.y *= inv; val.z *= inv; val.w *= inv;
    *(float4*)&hbuf[base] = val;
}

extern "C" void kernel_launch(void* const* d_in, const int* in_sizes, int n_in,
                              void* d_out, int out_size, void* d_ws, size_t ws_size,
                              hipStream_t stream) {
    const float* x         = (const float*)d_in[0];
    const float* edge_attr = (const float*)d_in[1];
    const int*   edge_index= (const int*)d_in[2];
    const float* WQ        = (const float*)d_in[3];
    const float* WK        = (const float*)d_in[4];
    const float* WV        = (const float*)d_in[5];
    const float* WE        = (const float*)d_in[6];

    const int N = in_sizes[0] / DIN;     // 50000
    const int E = in_sizes[2] / 2;       // 600000

    float* out   = (float*)d_out;
    float* h_out = out;                        // [N,128] — accumulated via atomics
    float* e_out = out + (long)N * DIN;        // [E,128]

    float* q = (float*)d_ws;                   // [N,128]
    float* k = q + (long)N * DIN;              // [N,128]
    float* v = k + (long)N * DIN;              // [N,128]
    float* z = v + (long)N * DIN;              // [N,8]

    // zero the atomic accumulators (d_out/d_ws are poisoned, not re-zeroed)
    hipMemsetAsync(h_out, 0, (size_t)N * DIN * sizeof(float), stream);
    hipMemsetAsync(z, 0, (size_t)N * NHEADS * sizeof(float), stream);

    node_proj_kernel<<<(N + NPB - 1) / NPB, 256, 0, stream>>>(x, WQ, WK, WV, q, k, v, N);
    edge_kernel<<<(E + EPB - 1) / EPB, 256, 0, stream>>>(edge_attr, edge_index, WE,
                                                         q, k, v, e_out, h_out, z, E);
    normalize_kernel<<<((long)N * DIN / 4 + 255) / 256, 256, 0, stream>>>(h_out, z, N);
}

// Round 2
// 708.191 us; speedup vs baseline: 1.8178x; 1.8178x over previous
//
#include <hip/hip_runtime.h>

#define DIN 128      // D_IN == N_HEADS*D_HEAD == 128
#define NHEADS 8
#define DHEAD 16
#define NPB 32       // nodes per block
#define EPB 32       // edges per block

__device__ __forceinline__ float clip5(float x) {
    return fminf(fmaxf(x, -5.0f), 5.0f);
}

// acc[i] (i=0..3, rows r0..r0+3) += xs[r0+i][:] @ W[:, cg*4 .. cg*4+3]
__device__ __forceinline__ void tile_gemm(const float xs[][DIN], int r0, int cg,
                                          const float* __restrict__ W,
                                          float4 acc[4]) {
#pragma unroll 4
    for (int kk = 0; kk < DIN; kk += 4) {
        float4 a[4];
#pragma unroll
        for (int i = 0; i < 4; ++i)
            a[i] = *(const float4*)&xs[r0 + i][kk];
#pragma unroll
        for (int t = 0; t < 4; ++t) {
            float4 w = *(const float4*)&W[(kk + t) * DIN + (cg << 2)];
#pragma unroll
            for (int i = 0; i < 4; ++i) {
                float av = ((const float*)&a[i])[t];
                acc[i].x = fmaf(av, w.x, acc[i].x);
                acc[i].y = fmaf(av, w.y, acc[i].y);
                acc[i].z = fmaf(av, w.z, acc[i].z);
                acc[i].w = fmaf(av, w.w, acc[i].w);
            }
        }
    }
}

__global__ __launch_bounds__(256) void node_proj_kernel(
    const float* __restrict__ x, const float* __restrict__ WQ,
    const float* __restrict__ WK, const float* __restrict__ WV,
    float* __restrict__ q, float* __restrict__ k, float* __restrict__ v,
    int N) {
    __shared__ float xs[NPB][DIN];
    const int tid = threadIdx.x;
    const int n0 = blockIdx.x * NPB;

#pragma unroll
    for (int i = 0; i < NPB * DIN / (256 * 4); ++i) {
        int idx = (tid + i * 256) * 4;
        int r = idx / DIN, c = idx % DIN;
        float4 val = make_float4(0.f, 0.f, 0.f, 0.f);
        if (n0 + r < N) val = *(const float4*)&x[(long)(n0 + r) * DIN + c];
        *(float4*)&xs[r][c] = val;
    }
    __syncthreads();

    const int cg = tid & 31;
    const int ng = tid >> 5;
    const int r0 = ng * 4;

    const float* Ws[3] = {WQ, WK, WV};
    float* outs[3] = {q, k, v};
#pragma unroll
    for (int m = 0; m < 3; ++m) {
        float4 acc[4] = {make_float4(0,0,0,0), make_float4(0,0,0,0),
                         make_float4(0,0,0,0), make_float4(0,0,0,0)};
        tile_gemm(xs, r0, cg, Ws[m], acc);
#pragma unroll
        for (int i = 0; i < 4; ++i) {
            int n = n0 + r0 + i;
            if (n < N)
                *(float4*)&outs[m][(long)n * DIN + (cg << 2)] = acc[i];
        }
    }
}

// ---------------- CSR build (counting sort by destination col) ----------------

__global__ __launch_bounds__(256) void degree_kernel(
    const int* __restrict__ cols, int* __restrict__ deg, int E) {
    int e = blockIdx.x * 256 + threadIdx.x;
    if (e < E) atomicAdd(&deg[cols[e]], 1);
}

__global__ __launch_bounds__(256) void block_sum_kernel(
    const int* __restrict__ deg, int* __restrict__ bsum, int N) {
    __shared__ int s[256];
    int tid = threadIdx.x;
    int i = blockIdx.x * 256 + tid;
    s[tid] = (i < N) ? deg[i] : 0;
    __syncthreads();
    for (int st = 128; st > 0; st >>= 1) {
        if (tid < st) s[tid] += s[tid + st];
        __syncthreads();
    }
    if (tid == 0) bsum[blockIdx.x] = s[0];
}

__global__ __launch_bounds__(256) void scan_bsum_kernel(int* __restrict__ bsum, int NB) {
    __shared__ int s[256];
    int tid = threadIdx.x;
    int v = (tid < NB) ? bsum[tid] : 0;
    s[tid] = v;
    __syncthreads();
    for (int off = 1; off < 256; off <<= 1) {
        int t = (tid >= off) ? s[tid - off] : 0;
        __syncthreads();
        s[tid] += t;
        __syncthreads();
    }
    if (tid < NB) bsum[tid] = s[tid] - v;   // exclusive
}

__global__ __launch_bounds__(256) void offsets_kernel(
    const int* __restrict__ deg, const int* __restrict__ bsumscan,
    int* __restrict__ offsets, int* __restrict__ cursor, int N, int E) {
    __shared__ int s[256];
    int tid = threadIdx.x;
    int i = blockIdx.x * 256 + tid;
    int v = (i < N) ? deg[i] : 0;
    s[tid] = v;
    __syncthreads();
    for (int off = 1; off < 256; off <<= 1) {
        int t = (tid >= off) ? s[tid - off] : 0;
        __syncthreads();
        s[tid] += t;
        __syncthreads();
    }
    int excl = s[tid] - v + bsumscan[blockIdx.x];
    if (i < N) { offsets[i] = excl; cursor[i] = excl; }
    if (blockIdx.x == 0 && tid == 0) offsets[N] = E;
}

__global__ __launch_bounds__(256) void scatter_kernel(
    const int* __restrict__ cols, int* __restrict__ cursor,
    int* __restrict__ elist, int E) {
    int e = blockIdx.x * 256 + threadIdx.x;
    if (e >= E) return;
    int pos = atomicAdd(&cursor[cols[e]], 1);
    elist[pos] = e;
}

// ---------------- edge compute: e_proj GEMM, e_out, ax ----------------

__global__ __launch_bounds__(256) void edge_compute_kernel(
    const float* __restrict__ edge_attr, const int* __restrict__ edge_index,
    const float* __restrict__ WE, const float* __restrict__ q,
    const float* __restrict__ k, float* __restrict__ e_out,
    float* __restrict__ ax, int E) {
    __shared__ float eas[EPB][DIN];
    __shared__ int rows[EPB], cols[EPB];
    const int tid = threadIdx.x;
    const int e0 = blockIdx.x * EPB;

    if (tid < EPB) {
        int e = e0 + tid;
        rows[tid] = (e < E) ? edge_index[e] : 0;
        cols[tid] = (e < E) ? edge_index[E + e] : 0;
    }
#pragma unroll
    for (int i = 0; i < EPB * DIN / (256 * 4); ++i) {
        int idx = (tid + i * 256) * 4;
        int r = idx / DIN, c = idx % DIN;
        float4 val = make_float4(0.f, 0.f, 0.f, 0.f);
        if (e0 + r < E) val = *(const float4*)&edge_attr[(long)(e0 + r) * DIN + c];
        *(float4*)&eas[r][c] = val;
    }
    __syncthreads();

    const int cg = tid & 31;
    const int ng = tid >> 5;
    const int r0 = ng * 4;

    float4 acc[4] = {make_float4(0,0,0,0), make_float4(0,0,0,0),
                     make_float4(0,0,0,0), make_float4(0,0,0,0)};
    tile_gemm(eas, r0, cg, WE, acc);

    const int h = cg >> 2;
#pragma unroll
    for (int i = 0; i < 4; ++i) {
        int el = r0 + i;
        if (e0 + el >= E) continue;
        int er = rows[el], ec = cols[el];
        float4 kv = *(const float4*)&k[(long)er * DIN + (cg << 2)];
        float4 qv = *(const float4*)&q[(long)ec * DIN + (cg << 2)];
        float4 t;
        t.x = clip5(kv.x * qv.x * 0.25f) * acc[i].x;
        t.y = clip5(kv.y * qv.y * 0.25f) * acc[i].y;
        t.z = clip5(kv.z * qv.z * 0.25f) * acc[i].z;
        t.w = clip5(kv.w * qv.w * 0.25f) * acc[i].w;
        *(float4*)&e_out[(long)(e0 + el) * DIN + (cg << 2)] = t;

        float s = t.x + t.y + t.z + t.w;
        s += __shfl_xor(s, 1);
        s += __shfl_xor(s, 2);
        if ((cg & 3) == 0)
            ax[(long)(e0 + el) * NHEADS + h] = expf(clip5(s));
    }
}

// ---------------- per-node gather aggregation (no atomics) ----------------

__global__ __launch_bounds__(256) void aggregate_kernel(
    const int* __restrict__ offsets, const int* __restrict__ elist,
    const int* __restrict__ rows, const float* __restrict__ ax,
    const float* __restrict__ v, float* __restrict__ h_out, int N) {
    int wid = blockIdx.x * 4 + (threadIdx.x >> 6);   // one wave per node
    int lane = threadIdx.x & 63;
    if (wid >= N) return;
    int beg = offsets[wid], end = offsets[wid + 1];
    const int head = lane >> 3;                      // dims lane*2, lane*2+1

    float2 acc = make_float2(0.f, 0.f);
    float zacc = 0.f;

    int e = 0, r = 0;
    if (beg < end) { e = elist[beg]; r = rows[e]; }
    for (int j = beg; j < end; ++j) {
        int en = 0, rn = 0;
        if (j + 1 < end) { en = elist[j + 1]; rn = rows[en]; }  // prefetch chain
        float a = ax[(long)e * NHEADS + head];
        float2 vv = *(const float2*)&v[(long)r * DIN + lane * 2];
        acc.x = fmaf(vv.x, a, acc.x);
        acc.y = fmaf(vv.y, a, acc.y);
        zacc += a;
        e = en; r = rn;
    }
    float inv = 1.0f / (zacc + 1e-6f);
    float2 res = make_float2(acc.x * inv, acc.y * inv);
    *(float2*)&h_out[(long)wid * DIN + lane * 2] = res;
}

extern "C" void kernel_launch(void* const* d_in, const int* in_sizes, int n_in,
                              void* d_out, int out_size, void* d_ws, size_t ws_size,
                              hipStream_t stream) {
    const float* x         = (const float*)d_in[0];
    const float* edge_attr = (const float*)d_in[1];
    const int*   edge_index= (const int*)d_in[2];
    const float* WQ        = (const float*)d_in[3];
    const float* WK        = (const float*)d_in[4];
    const float* WV        = (const float*)d_in[5];
    const float* WE        = (const float*)d_in[6];

    const int N = in_sizes[0] / DIN;     // 50000
    const int E = in_sizes[2] / 2;       // 600000
    const int NB = (N + 255) / 256;      // 196 scan blocks

    float* out   = (float*)d_out;
    float* h_out = out;                        // [N,128]
    float* e_out = out + (long)N * DIN;        // [E,128]

    // workspace layout (floats first, then ints)
    float* q  = (float*)d_ws;                  // [N,128]
    float* k  = q + (long)N * DIN;             // [N,128]
    float* v  = k + (long)N * DIN;             // [N,128]
    float* ax = v + (long)N * DIN;             // [E,8]
    int* ip      = (int*)(ax + (long)E * NHEADS);
    int* deg     = ip;                         // [N]
    int* cursor  = deg + N;                    // [N]
    int* offsets = cursor + N;                 // [N+1]
    int* bsum    = offsets + N + 1;            // [NB]
    int* elist   = bsum + 256;                 // [E]

    const int* rows = edge_index;              // [E]
    const int* cols = edge_index + E;          // [E]

    hipMemsetAsync(deg, 0, (size_t)N * sizeof(int), stream);

    node_proj_kernel<<<(N + NPB - 1) / NPB, 256, 0, stream>>>(x, WQ, WK, WV, q, k, v, N);

    degree_kernel<<<(E + 255) / 256, 256, 0, stream>>>(cols, deg, E);
    block_sum_kernel<<<NB, 256, 0, stream>>>(deg, bsum, N);
    scan_bsum_kernel<<<1, 256, 0, stream>>>(bsum, NB);
    offsets_kernel<<<NB, 256, 0, stream>>>(deg, bsum, offsets, cursor, N, E);
    scatter_kernel<<<(E + 255) / 256, 256, 0, stream>>>(cols, cursor, elist, E);

    edge_compute_kernel<<<(E + EPB - 1) / EPB, 256, 0, stream>>>(
        edge_attr, edge_index, WE, q, k, e_out, ax, E);

    aggregate_kernel<<<(N + 3) / 4, 256, 0, stream>>>(
        offsets, elist, rows, ax, v, h_out, N);
}

// Round 3
// 565.530 us; speedup vs baseline: 2.2764x; 1.2523x over previous
//
#include <hip/hip_runtime.h>

#define DIN 128      // D_IN == N_HEADS*D_HEAD == 128
#define NHEADS 8
#define DHEAD 16
#define NPB 32       // nodes per block (node_proj)
#define EPB 64       // edges per block (edge mfma kernel)

typedef __attribute__((ext_vector_type(8))) short short8;   // 8 bf16 (4 VGPRs)
typedef __attribute__((ext_vector_type(4))) float f32x4;    // MFMA C/D

__device__ __forceinline__ float clip5(float x) {
    return fminf(fmaxf(x, -5.0f), 5.0f);
}

__device__ __forceinline__ unsigned short f2bf(float f) {   // RNE f32->bf16
    unsigned u = __float_as_uint(f);
    unsigned r = (u + 0x7FFF + ((u >> 16) & 1)) >> 16;
    return (unsigned short)r;
}

// ---------------- node projections (fp32 VALU, small) ----------------

__device__ __forceinline__ void tile_gemm(const float xs[][DIN], int r0, int cg,
                                          const float* __restrict__ W,
                                          float4 acc[4]) {
#pragma unroll 4
    for (int kk = 0; kk < DIN; kk += 4) {
        float4 a[4];
#pragma unroll
        for (int i = 0; i < 4; ++i)
            a[i] = *(const float4*)&xs[r0 + i][kk];
#pragma unroll
        for (int t = 0; t < 4; ++t) {
            float4 w = *(const float4*)&W[(kk + t) * DIN + (cg << 2)];
#pragma unroll
            for (int i = 0; i < 4; ++i) {
                float av = ((const float*)&a[i])[t];
                acc[i].x = fmaf(av, w.x, acc[i].x);
                acc[i].y = fmaf(av, w.y, acc[i].y);
                acc[i].z = fmaf(av, w.z, acc[i].z);
                acc[i].w = fmaf(av, w.w, acc[i].w);
            }
        }
    }
}

__global__ __launch_bounds__(256) void node_proj_kernel(
    const float* __restrict__ x, const float* __restrict__ WQ,
    const float* __restrict__ WK, const float* __restrict__ WV,
    float* __restrict__ q, float* __restrict__ k, float* __restrict__ v,
    int N) {
    __shared__ float xs[NPB][DIN];
    const int tid = threadIdx.x;
    const int n0 = blockIdx.x * NPB;

#pragma unroll
    for (int i = 0; i < NPB * DIN / (256 * 4); ++i) {
        int idx = (tid + i * 256) * 4;
        int r = idx / DIN, c = idx % DIN;
        float4 val = make_float4(0.f, 0.f, 0.f, 0.f);
        if (n0 + r < N) val = *(const float4*)&x[(long)(n0 + r) * DIN + c];
        *(float4*)&xs[r][c] = val;
    }
    __syncthreads();

    const int cg = tid & 31;
    const int ng = tid >> 5;
    const int r0 = ng * 4;

    const float* Ws[3] = {WQ, WK, WV};
    float* outs[3] = {q, k, v};
#pragma unroll
    for (int m = 0; m < 3; ++m) {
        float4 acc[4] = {make_float4(0,0,0,0), make_float4(0,0,0,0),
                         make_float4(0,0,0,0), make_float4(0,0,0,0)};
        tile_gemm(xs, r0, cg, Ws[m], acc);
#pragma unroll
        for (int i = 0; i < 4; ++i) {
            int n = n0 + r0 + i;
            if (n < N)
                *(float4*)&outs[m][(long)n * DIN + (cg << 2)] = acc[i];
        }
    }
}

// ---------------- CSR build (counting sort by destination col) ----------------

__global__ __launch_bounds__(256) void degree_kernel(
    const int* __restrict__ cols, int* __restrict__ deg, int E) {
    int e = blockIdx.x * 256 + threadIdx.x;
    if (e < E) atomicAdd(&deg[cols[e]], 1);
}

__global__ __launch_bounds__(256) void block_sum_kernel(
    const int* __restrict__ deg, int* __restrict__ bsum, int N) {
    __shared__ int s[256];
    int tid = threadIdx.x;
    int i = blockIdx.x * 256 + tid;
    s[tid] = (i < N) ? deg[i] : 0;
    __syncthreads();
    for (int st = 128; st > 0; st >>= 1) {
        if (tid < st) s[tid] += s[tid + st];
        __syncthreads();
    }
    if (tid == 0) bsum[blockIdx.x] = s[0];
}

__global__ __launch_bounds__(256) void scan_bsum_kernel(int* __restrict__ bsum, int NB) {
    __shared__ int s[256];
    int tid = threadIdx.x;
    int v = (tid < NB) ? bsum[tid] : 0;
    s[tid] = v;
    __syncthreads();
    for (int off = 1; off < 256; off <<= 1) {
        int t = (tid >= off) ? s[tid - off] : 0;
        __syncthreads();
        s[tid] += t;
        __syncthreads();
    }
    if (tid < NB) bsum[tid] = s[tid] - v;   // exclusive
}

__global__ __launch_bounds__(256) void offsets_kernel(
    const int* __restrict__ deg, const int* __restrict__ bsumscan,
    int* __restrict__ offsets, int* __restrict__ cursor, int N, int E) {
    __shared__ int s[256];
    int tid = threadIdx.x;
    int i = blockIdx.x * 256 + tid;
    int v = (i < N) ? deg[i] : 0;
    s[tid] = v;
    __syncthreads();
    for (int off = 1; off < 256; off <<= 1) {
        int t = (tid >= off) ? s[tid - off] : 0;
        __syncthreads();
        s[tid] += t;
        __syncthreads();
    }
    int excl = s[tid] - v + bsumscan[blockIdx.x];
    if (i < N) { offsets[i] = excl; cursor[i] = excl; }
    if (blockIdx.x == 0 && tid == 0) offsets[N] = E;
}

__global__ __launch_bounds__(256) void scatter_kernel(
    const int* __restrict__ cols, int* __restrict__ cursor,
    int* __restrict__ elist, int E) {
    int e = blockIdx.x * 256 + threadIdx.x;
    if (e >= E) return;
    int pos = atomicAdd(&cursor[cols[e]], 1);
    elist[pos] = e;
}

// ---------------- WE -> bf16 transposed [n][k] ----------------

__global__ __launch_bounds__(256) void prep_wet_kernel(
    const float* __restrict__ WE, unsigned short* __restrict__ WEt) {
    int idx = blockIdx.x * 256 + threadIdx.x;    // 16384 total
    int kk = idx >> 7, n = idx & 127;
    WEt[n * DIN + kk] = f2bf(WE[kk * DIN + n]);
}

// ---------------- edge compute: MFMA e_proj + e_out + ax ----------------
// block: 256 threads = 4 waves, 64 edges. Wave w owns heads 2w, 2w+1 (32 cols).
// A (edges) staged bf16 in XOR-swizzled LDS; B (WEt) fragments live in VGPRs.

__global__ __launch_bounds__(256) void edge_mfma_kernel(
    const float* __restrict__ edge_attr, const int* __restrict__ edge_index,
    const unsigned short* __restrict__ WEt, const float* __restrict__ q,
    const float* __restrict__ k, float* __restrict__ e_out,
    float* __restrict__ ax, int E) {
    __shared__ unsigned short As[EPB * DIN];      // 16 KB, swizzled
    __shared__ int rows_s[EPB], cols_s[EPB];
    const int tid = threadIdx.x;
    const int e0 = blockIdx.x * EPB;              // E % EPB == 0

    if (tid < EPB) {
        rows_s[tid] = edge_index[e0 + tid];
        cols_s[tid] = edge_index[E + e0 + tid];
    }
    // stage edge_attr -> bf16 LDS (swizzle: 16B slot ^= row&7)
#pragma unroll
    for (int i = 0; i < EPB * DIN / (256 * 4); ++i) {    // 8 iters
        int idx = (tid + i * 256) * 4;
        int r = idx >> 7, c = idx & 127;
        float4 val = *(const float4*)&edge_attr[(long)(e0 + r) * DIN + c];
        ushort4 b;
        b.x = f2bf(val.x); b.y = f2bf(val.y); b.z = f2bf(val.z); b.w = f2bf(val.w);
        int byte = (r * 256 + c * 2) ^ ((r & 7) << 4);
        *(ushort4*)((char*)As + byte) = b;
    }

    const int w = tid >> 6;          // wave 0..3
    const int l = tid & 63;
    const int lr = l & 15;           // col-in-tile / row-for-A
    const int lg = l >> 4;           // k-group / row-group

    // B fragments: WEt[col][k], col = head*16+lr, k = ks*32 + lg*8 + 0..7
    short8 bfrag[2][4];
#pragma unroll
    for (int nt = 0; nt < 2; ++nt) {
        int col = (w * 2 + nt) * 16 + lr;
#pragma unroll
        for (int ks = 0; ks < 4; ++ks)
            bfrag[nt][ks] = *(const short8*)&WEt[col * DIN + ks * 32 + lg * 8];
    }

    __syncthreads();

    f32x4 acc[4][2];
#pragma unroll
    for (int mt = 0; mt < 4; ++mt)
#pragma unroll
        for (int nt = 0; nt < 2; ++nt)
            acc[mt][nt] = (f32x4){0.f, 0.f, 0.f, 0.f};

#pragma unroll
    for (int ks = 0; ks < 4; ++ks) {
#pragma unroll
        for (int mt = 0; mt < 4; ++mt) {
            int row = mt * 16 + lr;
            int byte = (row * 256 + (ks * 32 + lg * 8) * 2) ^ ((row & 7) << 4);
            short8 af = *(const short8*)((const char*)As + byte);
            acc[mt][0] = __builtin_amdgcn_mfma_f32_16x16x32_bf16(af, bfrag[0][ks], acc[mt][0], 0, 0, 0);
            acc[mt][1] = __builtin_amdgcn_mfma_f32_16x16x32_bf16(af, bfrag[1][ks], acc[mt][1], 0, 0, 0);
        }
    }

    // epilogue: C layout row = lg*4 + i (within 16), col = lr (within head tile)
#pragma unroll
    for (int mt = 0; mt < 4; ++mt) {
#pragma unroll
        for (int nt = 0; nt < 2; ++nt) {
            int h = w * 2 + nt;
            int col = h * 16 + lr;
#pragma unroll
            for (int i = 0; i < 4; ++i) {
                int r = mt * 16 + lg * 4 + i;
                int er = rows_s[r], ec = cols_s[r];
                float kv = k[(long)er * DIN + col];
                float qv = q[(long)ec * DIN + col];
                float t = clip5(kv * qv * 0.25f) * acc[mt][nt][i];
                e_out[(long)(e0 + r) * DIN + col] = t;
                float s = t;
                s += __shfl_xor(s, 1);
                s += __shfl_xor(s, 2);
                s += __shfl_xor(s, 4);
                s += __shfl_xor(s, 8);
                if (lr == 0)
                    ax[(long)(e0 + r) * NHEADS + h] = expf(clip5(s));
            }
        }
    }
}

// ---------------- per-node gather aggregation (no atomics) ----------------

__global__ __launch_bounds__(256) void aggregate_kernel(
    const int* __restrict__ offsets, const int* __restrict__ elist,
    const int* __restrict__ rows, const float* __restrict__ ax,
    const float* __restrict__ v, float* __restrict__ h_out, int N) {
    int wid = blockIdx.x * 4 + (threadIdx.x >> 6);   // one wave per node
    int lane = threadIdx.x & 63;
    if (wid >= N) return;
    int beg = offsets[wid], end = offsets[wid + 1];
    const int head = lane >> 3;

    float2 acc = make_float2(0.f, 0.f);
    float zacc = 0.f;

    int e = 0, r = 0;
    if (beg < end) { e = elist[beg]; r = rows[e]; }
    for (int j = beg; j < end; ++j) {
        int en = 0, rn = 0;
        if (j + 1 < end) { en = elist[j + 1]; rn = rows[en]; }
        float a = ax[(long)e * NHEADS + head];
        float2 vv = *(const float2*)&v[(long)r * DIN + lane * 2];
        acc.x = fmaf(vv.x, a, acc.x);
        acc.y = fmaf(vv.y, a, acc.y);
        zacc += a;
        e = en; r = rn;
    }
    float inv = 1.0f / (zacc + 1e-6f);
    float2 res = make_float2(acc.x * inv, acc.y * inv);
    *(float2*)&h_out[(long)wid * DIN + lane * 2] = res;
}

extern "C" void kernel_launch(void* const* d_in, const int* in_sizes, int n_in,
                              void* d_out, int out_size, void* d_ws, size_t ws_size,
                              hipStream_t stream) {
    const float* x         = (const float*)d_in[0];
    const float* edge_attr = (const float*)d_in[1];
    const int*   edge_index= (const int*)d_in[2];
    const float* WQ        = (const float*)d_in[3];
    const float* WK        = (const float*)d_in[4];
    const float* WV        = (const float*)d_in[5];
    const float* WE        = (const float*)d_in[6];

    const int N = in_sizes[0] / DIN;     // 50000
    const int E = in_sizes[2] / 2;       // 600000 (multiple of 64)
    const int NB = (N + 255) / 256;

    float* out   = (float*)d_out;
    float* h_out = out;                        // [N,128]
    float* e_out = out + (long)N * DIN;        // [E,128]

    float* q  = (float*)d_ws;                  // [N,128]
    float* k  = q + (long)N * DIN;             // [N,128]
    float* v  = k + (long)N * DIN;             // [N,128]
    float* ax = v + (long)N * DIN;             // [E,8]
    unsigned short* WEt = (unsigned short*)(ax + (long)E * NHEADS);  // [128,128] bf16
    int* ip      = (int*)(WEt + DIN * DIN);
    int* deg     = ip;                         // [N]
    int* cursor  = deg + N;                    // [N]
    int* offsets = cursor + N;                 // [N+1]
    int* bsum    = offsets + N + 1;            // [NB]
    int* elist   = bsum + 256;                 // [E]

    const int* rows = edge_index;
    const int* cols = edge_index + E;

    hipMemsetAsync(deg, 0, (size_t)N * sizeof(int), stream);

    node_proj_kernel<<<(N + NPB - 1) / NPB, 256, 0, stream>>>(x, WQ, WK, WV, q, k, v, N);
    prep_wet_kernel<<<DIN * DIN / 256, 256, 0, stream>>>(WE, WEt);

    degree_kernel<<<(E + 255) / 256, 256, 0, stream>>>(cols, deg, E);
    block_sum_kernel<<<NB, 256, 0, stream>>>(deg, bsum, N);
    scan_bsum_kernel<<<1, 256, 0, stream>>>(bsum, NB);
    offsets_kernel<<<NB, 256, 0, stream>>>(deg, bsum, offsets, cursor, N, E);
    scatter_kernel<<<(E + 255) / 256, 256, 0, stream>>>(cols, cursor, elist, E);

    edge_mfma_kernel<<<E / EPB, 256, 0, stream>>>(
        edge_attr, edge_index, WEt, q, k, e_out, ax, E);

    aggregate_kernel<<<(N + 3) / 4, 256, 0, stream>>>(
        offsets, elist, rows, ax, v, h_out, N);
}